// Round 1
// baseline (1846.167 us; speedup 1.0000x reference)
//
#include <hip/hip_runtime.h>

// Problem constants
#define BB 16
#define LL 4096
#define HH 8
#define NN 64
#define DD 128   // Din == M
#define NCH 64   // chunks along L
#define LCH 64   // chunk length

// Workspace layout (float offsets)
#define OFF_A_RE   0
#define OFF_A_IM   512
#define OFF_ALC_RE 1024
#define OFF_ALC_IM 1536
#define OFF_BB_RE  2048
#define OFF_BB_IM  (2048 + 65536)
#define OFF_S_RE   (2048 + 2 * 65536)
#define OFF_S_IM   (OFF_S_RE + 524288)
// total = 1,181,696 floats = ~4.73 MB

// K0: per (h,n) discretization: A_bar, A_bar^LC, B_bar = B_coef * B
__global__ __launch_bounds__(256) void k0_precompute(
    const float* __restrict__ Lre, const float* __restrict__ Lim,
    const float* __restrict__ Bre, const float* __restrict__ Bim,
    const float* __restrict__ logdt, float* __restrict__ W)
{
    int gid = blockIdx.x * 256 + threadIdx.x;
    if (gid >= HH * NN) return;
    float lre = Lre[gid], lim = Lim[gid];
    float lam_re = -log1pf(expf(lre));     // -softplus
    float lam_im = lim;
    float delta = expf(logdt[gid]);
    float lbr = lam_re * delta, lbi = lam_im * delta;
    float ea = expf(lbr);
    float Ar = ea * cosf(lbi), Ai = ea * sinf(lbi);
    float el = expf(lbr * (float)LCH);
    float ALr = el * cosf(lbi * (float)LCH), ALi = el * sinf(lbi * (float)LCH);
    float den = lam_re * lam_re + lam_im * lam_im + 1e-7f;
    float rr = lam_re / den, ri = -lam_im / den;   // conj(Lam)/(|Lam|^2+eps)
    float am1 = Ar - 1.f;
    float bcr = rr * am1 - ri * Ai;
    float bci = rr * Ai + ri * am1;
    W[OFF_A_RE + gid] = Ar;   W[OFF_A_IM + gid] = Ai;
    W[OFF_ALC_RE + gid] = ALr; W[OFF_ALC_IM + gid] = ALi;
    const float* brp = Bre + (size_t)gid * DD;
    const float* bip = Bim + (size_t)gid * DD;
    float* wr = W + OFF_BB_RE + (size_t)gid * DD;
    float* wi = W + OFF_BB_IM + (size_t)gid * DD;
    for (int d = 0; d < DD; ++d) {
        float br = brp[d], bi = bip[d];
        wr[d] = bcr * br - bci * bi;
        wi[d] = bcr * bi + bci * br;
    }
}

// K1: per (b,h,chunk): local final state S = sum_k a^(LC-1-k) * Bu_k
// 4 waves = 4 d-quarters (B_bar quarter in regs), lane = n, k-loop descending.
__global__ __launch_bounds__(256) void k1_chunk_state(
    const float* __restrict__ u, float* __restrict__ W)
{
    __shared__ float red[2][4][NN];
    int bid = blockIdx.x;
    int c = bid & 63, bh = bid >> 6;
    int h = bh & 7, b = bh >> 3;
    int tid = threadIdx.x;
    int n = tid & 63, q = tid >> 6;
    int hn = h * NN + n;
    float ar = W[OFF_A_RE + hn], ai = W[OFF_A_IM + hn];
    const float4* br4 = (const float4*)(W + OFF_BB_RE + (size_t)hn * DD + q * 32);
    const float4* bi4 = (const float4*)(W + OFF_BB_IM + (size_t)hn * DD + q * 32);
    float4 brr[8], bri[8];
    #pragma unroll
    for (int j = 0; j < 8; ++j) { brr[j] = br4[j]; bri[j] = bi4[j]; }
    const float* ubase = u + ((size_t)b * LL + (size_t)c * LCH) * DD + q * 32;
    float pr = 1.f, pi = 0.f;          // a^(LC-1-k), k descending from LC-1
    float sr = 0.f, si = 0.f;
    for (int k = LCH - 1; k >= 0; --k) {
        const float4* u4 = (const float4*)(ubase + (size_t)k * DD);
        float bur = 0.f, bui = 0.f;
        #pragma unroll
        for (int j = 0; j < 8; ++j) {
            float4 uv = u4[j];
            float4 br = brr[j], bi = bri[j];
            bur += uv.x * br.x + uv.y * br.y + uv.z * br.z + uv.w * br.w;
            bui += uv.x * bi.x + uv.y * bi.y + uv.z * bi.z + uv.w * bi.w;
        }
        sr += pr * bur - pi * bui;
        si += pr * bui + pi * bur;
        float npr = pr * ar - pi * ai;
        pi = pr * ai + pi * ar;
        pr = npr;
    }
    red[0][q][n] = sr; red[1][q][n] = si;
    __syncthreads();
    if (tid < NN) {
        float s0 = red[0][0][tid] + red[0][1][tid] + red[0][2][tid] + red[0][3][tid];
        float s1 = red[1][0][tid] + red[1][1][tid] + red[1][2][tid] + red[1][3][tid];
        size_t sidx = ((size_t)bh * NCH + c) * NN + tid;
        W[OFF_S_RE + sidx] = s0;
        W[OFF_S_IM + sidx] = s1;
    }
}

// K2: cross-chunk exclusive scan, in place over S (S[c] becomes x_init of chunk c)
__global__ __launch_bounds__(256) void k2_chunk_scan(float* __restrict__ W)
{
    int gid = blockIdx.x * 256 + threadIdx.x;   // 8192 = B*H*N
    int n = gid & 63, bh = gid >> 6;
    int h = bh & 7;
    int hn = h * NN + n;
    float alr = W[OFF_ALC_RE + hn], ali = W[OFF_ALC_IM + hn];
    float xr = 0.f, xi = 0.f;
    size_t base = (size_t)bh * NCH * NN + n;
    for (int c = 0; c < NCH; ++c) {
        size_t idx = base + (size_t)c * NN;
        float sr = W[OFF_S_RE + idx], si = W[OFF_S_IM + idx];
        W[OFF_S_RE + idx] = xr;
        W[OFF_S_IM + idx] = xi;
        float nxr = alr * xr - ali * xi + sr;
        float nxi = alr * xi + ali * xr + si;
        xr = nxr; xi = nxi;
    }
}

// K3: per (b,h,chunk): recompute Bu -> LDS, scan with x_init, y = 2Re(Cx)+Du
__global__ __launch_bounds__(256) void k3_output(
    const float* __restrict__ u,
    const float* __restrict__ Cre, const float* __restrict__ Cim,
    const float* __restrict__ Dp,
    float* __restrict__ W, float* __restrict__ y)
{
    __shared__ float uly[LCH * DD];      // staged u chunk; reused as y-partials
    __shared__ float xr[LCH][NN];
    __shared__ float xi_s[LCH][NN];
    int bid = blockIdx.x;
    int c = bid & 63, bh = bid >> 6;
    int h = bh & 7, b = bh >> 3;
    int tid = threadIdx.x;
    const float* usrc = u + ((size_t)b * LL + (size_t)c * LCH) * DD;
    {   // stage u chunk (coalesced float4)
        const float4* s4 = (const float4*)usrc;
        float4* d4 = (float4*)uly;
        #pragma unroll
        for (int i = 0; i < 8; ++i) d4[tid + 256 * i] = s4[tid + 256 * i];
    }
    int n = tid & 63, q = tid >> 6;
    int hn = h * NN + n;
    float ar = W[OFF_A_RE + hn], ai = W[OFF_A_IM + hn];
    const float4* br4 = (const float4*)(W + OFF_BB_RE + (size_t)hn * DD + q * 32);
    const float4* bi4 = (const float4*)(W + OFF_BB_IM + (size_t)hn * DD + q * 32);
    float4 brr[8], bri[8];
    #pragma unroll
    for (int j = 0; j < 8; ++j) { brr[j] = br4[j]; bri[j] = bi4[j]; }
    __syncthreads();
    // Phase A: Bu[t][n] accumulated across 4 d-quarters, rotating t-block ownership
    for (int s = 0; s < 4; ++s) {
        int tb = (q + s) & 3;
        for (int i = 0; i < 16; ++i) {
            int t = tb * 16 + i;
            const float4* u4 = (const float4*)(uly + t * DD + q * 32);
            float bur = 0.f, bui = 0.f;
            #pragma unroll
            for (int j = 0; j < 8; ++j) {
                float4 uv = u4[j];
                float4 br = brr[j], bi = bri[j];
                bur += uv.x * br.x + uv.y * br.y + uv.z * br.z + uv.w * br.w;
                bui += uv.x * bi.x + uv.y * bi.y + uv.z * bi.z + uv.w * bi.w;
            }
            if (s == 0) { xr[t][n] = bur;  xi_s[t][n] = bui; }
            else        { xr[t][n] += bur; xi_s[t][n] += bui; }
        }
        __syncthreads();
    }
    // Phase B: serial scan over the chunk (wave 0, lane = n)
    if (tid < NN) {
        size_t sidx = ((size_t)bh * NCH + c) * NN + tid;
        float xcr = W[OFF_S_RE + sidx], xci = W[OFF_S_IM + sidx];
        for (int t = 0; t < LCH; ++t) {
            float bur = xr[t][tid], bui = xi_s[t][tid];
            float nr = ar * xcr - ai * xci + bur;
            float ni = ar * xci + ai * xcr + bui;
            xr[t][tid] = nr; xi_s[t][tid] = ni;
            xcr = nr; xci = ni;
        }
    }
    __syncthreads();
    // Phase C: y[t][m] = 2*(Cre.xr - Cim.xi) + D*u ; 2 n-halves, C rows in regs
    int m = tid & 127, half = tid >> 7;
    const float4* cr4 = (const float4*)(Cre + ((size_t)h * DD + m) * NN + half * 32);
    const float4* ci4 = (const float4*)(Cim + ((size_t)h * DD + m) * NN + half * 32);
    float4 crr[8], cri[8];
    #pragma unroll
    for (int j = 0; j < 8; ++j) { crr[j] = cr4[j]; cri[j] = ci4[j]; }
    float dm = Dp[h * DD + m];
    float* ypart = uly;   // reuse (u re-read from global for the D term)
    float* yout = y + (((size_t)b * LL + (size_t)c * LCH) * HH + h) * DD + m;
    for (int tt = 0; tt < 8; ++tt) {
        float part[8];
        #pragma unroll
        for (int i = 0; i < 8; ++i) {
            int t = tt * 8 + i;
            const float4* xr4 = (const float4*)(&xr[t][half * 32]);
            const float4* xi4 = (const float4*)(&xi_s[t][half * 32]);
            float acc = 0.f;
            #pragma unroll
            for (int j = 0; j < 8; ++j) {
                float4 xrv = xr4[j], xiv = xi4[j];
                float4 cr = crr[j], ci = cri[j];
                acc += cr.x * xrv.x + cr.y * xrv.y + cr.z * xrv.z + cr.w * xrv.w;
                acc -= ci.x * xiv.x + ci.y * xiv.y + ci.z * xiv.z + ci.w * xiv.w;
            }
            part[i] = acc;
        }
        if (half == 1) {
            #pragma unroll
            for (int i = 0; i < 8; ++i) ypart[i * DD + m] = part[i];
        }
        __syncthreads();
        if (half == 0) {
            #pragma unroll
            for (int i = 0; i < 8; ++i) {
                int t = tt * 8 + i;
                float yv = 2.f * (part[i] + ypart[i * DD + m]) + dm * usrc[(size_t)t * DD + m];
                yout[(size_t)t * HH * DD] = yv;
            }
        }
        __syncthreads();
    }
}

extern "C" void kernel_launch(void* const* d_in, const int* in_sizes, int n_in,
                              void* d_out, int out_size, void* d_ws, size_t ws_size,
                              hipStream_t stream)
{
    const float* u   = (const float*)d_in[0];
    const float* Lre = (const float*)d_in[1];
    const float* Lim = (const float*)d_in[2];
    const float* Bre = (const float*)d_in[3];
    const float* Bim = (const float*)d_in[4];
    const float* Cre = (const float*)d_in[5];
    const float* Cim = (const float*)d_in[6];
    const float* ldt = (const float*)d_in[7];
    const float* Dp  = (const float*)d_in[8];
    float* W = (float*)d_ws;
    float* y = (float*)d_out;

    hipLaunchKernelGGL(k0_precompute, dim3(2), dim3(256), 0, stream,
                       Lre, Lim, Bre, Bim, ldt, W);
    hipLaunchKernelGGL(k1_chunk_state, dim3(BB * HH * NCH), dim3(256), 0, stream, u, W);
    hipLaunchKernelGGL(k2_chunk_scan, dim3(32), dim3(256), 0, stream, W);
    hipLaunchKernelGGL(k3_output, dim3(BB * HH * NCH), dim3(256), 0, stream,
                       u, Cre, Cim, Dp, W, y);
}

// Round 2
// 468.416 us; speedup vs baseline: 3.9413x; 3.9413x over previous
//
#include <hip/hip_runtime.h>

typedef short short8 __attribute__((ext_vector_type(8)));
typedef float f32x4 __attribute__((ext_vector_type(4)));

#define BB 16
#define LL 4096
#define HH 8
#define NN 64
#define DD 128
#define NCH 64
#define LCH 64

// fp32 region of workspace (float offsets)
#define OFF_A_RE   0
#define OFF_A_IM   512
#define OFF_P16    1024          // [3][2][512] : A^16, A^32, A^48
#define OFF_A64_RE 4096
#define OFF_A64_IM 4608
// byte offsets within workspace
#define SB_RE_BYTE  20480        // bf16 S real: 524288 ushorts = 1 MB
#define SB_IM_BYTE  1069056      // bf16 S imag
#define PACKB_BYTE  2117632      // 262144 B : [h][ntile4][ri2][kk4][lane64][8] bf16
#define PACKC_BYTE  2379776      // 262144 B : [h][mtile8][ri2][kk2][lane64][8] bf16
// total ws use: 2641920 B (~2.5 MB)

__device__ __forceinline__ unsigned short f2bf(float x) {
    unsigned u = __float_as_uint(x);
    return (unsigned short)((u + 0x7FFFu + ((u >> 16) & 1u)) >> 16);
}
__device__ __forceinline__ float bf2f(unsigned short v) {
    return __uint_as_float(((unsigned)v) << 16);
}

// ---------------- k0: discretize, A-powers, pack B_bar fragments ----------------
__global__ __launch_bounds__(256) void k0_precompute(
    const float* __restrict__ Lre, const float* __restrict__ Lim,
    const float* __restrict__ Bre, const float* __restrict__ Bim,
    const float* __restrict__ logdt, float* __restrict__ W,
    short* __restrict__ packB)
{
    int gid = blockIdx.x * 256 + threadIdx.x;    // h*64 + n
    if (gid >= HH * NN) return;
    float lam_re = -log1pf(expf(Lre[gid]));
    float lam_im = Lim[gid];
    float delta = expf(logdt[gid]);
    float lbr = lam_re * delta, lbi = lam_im * delta;
    float ea = expf(lbr);
    float Ar = ea * cosf(lbi), Ai = ea * sinf(lbi);
    // complex powers by squaring
    float p2r = Ar*Ar - Ai*Ai,   p2i = 2.f*Ar*Ai;
    float p4r = p2r*p2r - p2i*p2i, p4i = 2.f*p2r*p2i;
    float p8r = p4r*p4r - p4i*p4i, p8i = 2.f*p4r*p4i;
    float p16r = p8r*p8r - p8i*p8i, p16i = 2.f*p8r*p8i;
    float p32r = p16r*p16r - p16i*p16i, p32i = 2.f*p16r*p16i;
    float p48r = p32r*p16r - p32i*p16i, p48i = p32r*p16i + p32i*p16r;
    float p64r = p32r*p32r - p32i*p32i, p64i = 2.f*p32r*p32i;
    W[OFF_A_RE + gid] = Ar;  W[OFF_A_IM + gid] = Ai;
    W[OFF_P16 + 0*1024 + gid]       = p16r; W[OFF_P16 + 0*1024 + 512 + gid] = p16i;
    W[OFF_P16 + 1*1024 + gid]       = p32r; W[OFF_P16 + 1*1024 + 512 + gid] = p32i;
    W[OFF_P16 + 2*1024 + gid]       = p48r; W[OFF_P16 + 2*1024 + 512 + gid] = p48i;
    W[OFF_A64_RE + gid] = p64r; W[OFF_A64_IM + gid] = p64i;
    // B_coef = conj(Lam)/(|Lam|^2+eps) * (A-1)
    float den = lam_re*lam_re + lam_im*lam_im + 1e-7f;
    float rr = lam_re / den, rim = -lam_im / den;
    float am1 = Ar - 1.f;
    float bcr = rr * am1 - rim * Ai;
    float bci = rr * Ai + rim * am1;
    // pack B_bar[n][d] into MFMA-B fragment order (k = d)
    int h = gid >> 6, n = gid & 63;
    int ntile = n >> 4, nl = n & 15;
    const float* brp = Bre + (size_t)gid * DD;
    const float* bip = Bim + (size_t)gid * DD;
    for (int dblk = 0; dblk < 16; ++dblk) {
        int kk = dblk >> 2, dh = dblk & 3;
        int lane = nl | (dh << 4);
        size_t g = (size_t)h*16384 + (size_t)ntile*4096 + (size_t)kk*512 + (size_t)lane*8;
        short8 vr, vi;
        #pragma unroll
        for (int j = 0; j < 8; ++j) {
            int d = dblk * 8 + j;
            float br = brp[d], bi = bip[d];
            vr[j] = (short)f2bf(bcr * br - bci * bi);
            vi[j] = (short)f2bf(bcr * bi + bci * br);
        }
        *(short8*)(packB + g)        = vr;   // ri = 0
        *(short8*)(packB + g + 2048) = vi;   // ri = 1
    }
}

// ---------------- k0c: pack C fragments (scale 2, -2 folded in) ----------------
__global__ __launch_bounds__(256) void k0c_packC(
    const float* __restrict__ Cre, const float* __restrict__ Cim,
    short* __restrict__ packC)
{
    int gid = blockIdx.x * 256 + threadIdx.x;   // [h][mtile][ri][kk][lane] = 16384
    int h = gid >> 11, r = gid & 2047;
    int mtile = r >> 8; int r2 = r & 255;
    int ri = r2 >> 7; int r3 = r2 & 127;
    int kk = r3 >> 6; int lane = r3 & 63;
    int m = mtile * 16 + (lane & 15);
    int nbase = 8 * (lane >> 4) + 32 * kk;
    const float* src = (ri ? Cim : Cre) + ((size_t)h * DD + m) * NN + nbase;
    float sc = ri ? -2.f : 2.f;
    short8 v;
    #pragma unroll
    for (int j = 0; j < 8; ++j) v[j] = (short)f2bf(sc * src[j]);
    *(short8*)(packC + (size_t)gid * 8) = v;
}

// ---------------- shared device pieces ----------------
// stage u chunk (fp32 global) -> bf16 LDS [64][128], XOR-swizzled 16B granules
__device__ __forceinline__ void stage_u(const float* __restrict__ usrc,
                                        char* __restrict__ uLDS, int tid)
{
    #pragma unroll
    for (int i = 0; i < 4; ++i) {
        int g = tid + 256 * i;
        int row = g >> 4, gc = g & 15;
        const float4* s = (const float4*)(usrc + (size_t)row * DD + gc * 8);
        float4 a = s[0], b = s[1];
        short8 v;
        v[0]=(short)f2bf(a.x); v[1]=(short)f2bf(a.y); v[2]=(short)f2bf(a.z); v[3]=(short)f2bf(a.w);
        v[4]=(short)f2bf(b.x); v[5]=(short)f2bf(b.y); v[6]=(short)f2bf(b.z); v[7]=(short)f2bf(b.w);
        int byte = (gc * 16) ^ ((row & 7) << 4);
        *(short8*)(uLDS + row * 256 + byte) = v;
    }
}

// Bu GEMM: u[64t x 128d] (LDS bf16) x B_bar^T[128d x 64n] (packed global) -> xr/xi [t][n] fp32 LDS
__device__ __forceinline__ void bu_mfma(const char* __restrict__ uLDS,
                                        const short* __restrict__ packBh,
                                        int w, int l,
                                        float* __restrict__ xrL, float* __restrict__ xiL)
{
    int lrow = l & 15, lhi = l >> 4;
    int trow = 16 * w + lrow;
    short8 af[4];
    #pragma unroll
    for (int kk = 0; kk < 4; ++kk) {
        int byte = (16 * lhi + 64 * kk) ^ ((trow & 7) << 4);
        af[kk] = *(const short8*)(uLDS + trow * 256 + byte);
    }
    f32x4 z = {0.f, 0.f, 0.f, 0.f};
    f32x4 acc[4][2];
    #pragma unroll
    for (int nt = 0; nt < 4; ++nt) { acc[nt][0] = z; acc[nt][1] = z; }
    #pragma unroll
    for (int nt = 0; nt < 4; ++nt)
        #pragma unroll
        for (int ri = 0; ri < 2; ++ri)
            #pragma unroll
            for (int kk = 0; kk < 4; ++kk) {
                short8 bf = *(const short8*)(packBh + nt*4096 + ri*2048 + kk*512 + l*8);
                acc[nt][ri] = __builtin_amdgcn_mfma_f32_16x16x32_bf16(af[kk], bf, acc[nt][ri], 0, 0, 0);
            }
    #pragma unroll
    for (int nt = 0; nt < 4; ++nt) {
        int n = 16 * nt + lrow;
        #pragma unroll
        for (int r = 0; r < 4; ++r) {
            int t = 16 * w + 4 * lhi + r;
            xrL[t * 68 + n] = acc[nt][0][r];
            xiL[t * 68 + n] = acc[nt][1][r];
        }
    }
}

// ---------------- k1: chunk-final state S ----------------
__global__ __launch_bounds__(256, 3) void k1_chunk_state(
    const float* __restrict__ u, const float* __restrict__ W,
    const short* __restrict__ packB,
    unsigned short* __restrict__ SR, unsigned short* __restrict__ SI)
{
    __shared__ __align__(16) char reg0[16384];
    __shared__ __align__(16) float reg1[2 * 64 * 68];
    __shared__ float red[2][4][NN];
    float* xrL = reg1;
    float* xiL = reg1 + 64 * 68;
    int bid = blockIdx.x;
    int c = bid & 63, bh = bid >> 6;
    int h = bh & 7;
    int tid = threadIdx.x;
    int w = tid >> 6, l = tid & 63;
    const float* usrc = u + ((size_t)(bh >> 3) * LL + (size_t)c * LCH) * DD;
    stage_u(usrc, reg0, tid);
    __syncthreads();
    bu_mfma(reg0, packB + (size_t)h * 16384, w, l, xrL, xiL);
    __syncthreads();
    // weighted reduce: S = sum_t A^(63-t) * Bu[t]
    int n = l, tq = w;
    int hn = h * NN + n;
    float ar = W[OFF_A_RE + hn], ai = W[OFF_A_IM + hn];
    float wr, wi;
    if (tq == 3) { wr = 1.f; wi = 0.f; }
    else { wr = W[OFF_P16 + (2 - tq) * 1024 + hn]; wi = W[OFF_P16 + (2 - tq) * 1024 + 512 + hn]; }
    float sr = 0.f, si = 0.f;
    for (int i = 15; i >= 0; --i) {
        int t = tq * 16 + i;
        float br = xrL[t * 68 + n], bi = xiL[t * 68 + n];
        sr += wr * br - wi * bi;
        si += wr * bi + wi * br;
        float nwr = wr * ar - wi * ai;
        wi = wr * ai + wi * ar;
        wr = nwr;
    }
    red[0][tq][n] = sr; red[1][tq][n] = si;
    __syncthreads();
    if (tid < NN) {
        float s0 = red[0][0][tid] + red[0][1][tid] + red[0][2][tid] + red[0][3][tid];
        float s1 = red[1][0][tid] + red[1][1][tid] + red[1][2][tid] + red[1][3][tid];
        size_t sidx = ((size_t)bh * NCH + c) * NN + tid;
        SR[sidx] = f2bf(s0);
        SI[sidx] = f2bf(s1);
    }
}

// ---------------- k2: cross-chunk exclusive scan (in place, bf16 storage) ----------------
__global__ __launch_bounds__(256) void k2_chunk_scan(
    const float* __restrict__ W,
    unsigned short* __restrict__ SR, unsigned short* __restrict__ SI)
{
    int gid = blockIdx.x * 256 + threadIdx.x;   // 8192 = B*H*N
    int n = gid & 63, bh = gid >> 6;
    int h = bh & 7;
    int hn = h * NN + n;
    float alr = W[OFF_A64_RE + hn], ali = W[OFF_A64_IM + hn];
    float xr = 0.f, xi = 0.f;
    size_t base = (size_t)bh * NCH * NN + n;
    for (int c = 0; c < NCH; ++c) {
        size_t idx = base + (size_t)c * NN;
        float sr = bf2f(SR[idx]), si = bf2f(SI[idx]);
        SR[idx] = f2bf(xr); SI[idx] = f2bf(xi);
        float nxr = fmaf(alr, xr, fmaf(-ali, xi, sr));
        float nxi = fmaf(alr, xi, fmaf(ali, xr, si));
        xr = nxr; xi = nxi;
    }
}

// ---------------- k3: Bu (MFMA) -> scan -> y = Cx (MFMA) + D*u ----------------
__global__ __launch_bounds__(256, 3) void k3_output(
    const float* __restrict__ u, const float* __restrict__ Dp,
    const float* __restrict__ W,
    const short* __restrict__ packB, const short* __restrict__ packC,
    const unsigned short* __restrict__ SR, const unsigned short* __restrict__ SI,
    float* __restrict__ y)
{
    __shared__ __align__(16) char reg0[16384];        // u bf16; later x bf16 (re 0..8191, im 8192..)
    __shared__ __align__(16) float reg1[2 * 64 * 68]; // xr/xi fp32; later ytile [64][132]
    float* xrL = reg1;
    float* xiL = reg1 + 64 * 68;
    int bid = blockIdx.x;
    int c = bid & 63, bh = bid >> 6;
    int h = bh & 7;
    int tid = threadIdx.x;
    int w = tid >> 6, l = tid & 63;
    const float* usrc = u + ((size_t)(bh >> 3) * LL + (size_t)c * LCH) * DD;
    stage_u(usrc, reg0, tid);
    __syncthreads();
    bu_mfma(reg0, packB + (size_t)h * 16384, w, l, xrL, xiL);
    __syncthreads();
    // serial in-chunk scan, wave 0 (lane = n), fp32
    if (tid < NN) {
        int hn = h * NN + tid;
        float ar = W[OFF_A_RE + hn], ai = W[OFF_A_IM + hn];
        size_t sidx = ((size_t)bh * NCH + c) * NN + tid;
        float xcr = bf2f(SR[sidx]), xci = bf2f(SI[sidx]);
        float cr = xrL[tid], ci = xiL[tid];
        for (int t = 0; t < LCH; ++t) {
            float nbr = 0.f, nbi = 0.f;
            if (t < 63) { nbr = xrL[(t + 1) * 68 + tid]; nbi = xiL[(t + 1) * 68 + tid]; }
            float nr = fmaf(ar, xcr, fmaf(-ai, xci, cr));
            float ni = fmaf(ar, xci, fmaf(ai, xcr, ci));
            xrL[t * 68 + tid] = nr; xiL[t * 68 + tid] = ni;
            xcr = nr; xci = ni; cr = nbr; ci = nbi;
        }
    }
    __syncthreads();
    // cast x -> bf16 into reg0 (swizzled), re at 0, im at 8192
    {
        int trow = tid >> 2, cb = tid & 3;
        const float* pr = xrL + trow * 68 + cb * 16;
        const float* pi = xiL + trow * 68 + cb * 16;
        #pragma unroll
        for (int g = 0; g < 2; ++g) {
            short8 vr, vi;
            #pragma unroll
            for (int j = 0; j < 8; ++j) {
                vr[j] = (short)f2bf(pr[g * 8 + j]);
                vi[j] = (short)f2bf(pi[g * 8 + j]);
            }
            int byte = (cb * 32 + g * 16) ^ ((trow & 7) << 4);
            *(short8*)(reg0 + trow * 128 + byte) = vr;
            *(short8*)(reg0 + 8192 + trow * 128 + byte) = vi;
        }
    }
    __syncthreads();
    // y GEMM: x[64t x 64n] (bf16 LDS) x C^T[64n x 128m] (packed, 2/-2 folded) -> ytile
    float* yt = reg1;   // [64][132] fp32 (xr/xi dead)
    {
        int lrow = l & 15, lhi = l >> 4;
        int trow = 16 * w + lrow;
        short8 af[2][2];
        #pragma unroll
        for (int ri = 0; ri < 2; ++ri)
            #pragma unroll
            for (int kk = 0; kk < 2; ++kk) {
                int byte = (16 * lhi + 64 * kk) ^ ((trow & 7) << 4);
                af[ri][kk] = *(const short8*)(reg0 + ri * 8192 + trow * 128 + byte);
            }
        const short* packCh = packC + (size_t)h * 16384;
        #pragma unroll
        for (int mt = 0; mt < 8; ++mt) {
            f32x4 acc = {0.f, 0.f, 0.f, 0.f};
            #pragma unroll
            for (int ri = 0; ri < 2; ++ri)
                #pragma unroll
                for (int kk = 0; kk < 2; ++kk) {
                    short8 cf = *(const short8*)(packCh + mt*2048 + ri*1024 + kk*512 + l*8);
                    acc = __builtin_amdgcn_mfma_f32_16x16x32_bf16(af[ri][kk], cf, acc, 0, 0, 0);
                }
            #pragma unroll
            for (int r = 0; r < 4; ++r)
                yt[(16 * w + 4 * lhi + r) * 132 + 16 * mt + lrow] = acc[r];
        }
    }
    __syncthreads();
    // epilogue: y = ytile + D*u, coalesced float4 store
    const float* Dh = Dp + h * DD;
    float* yout = y + (((size_t)(bh >> 3) * LL + (size_t)c * LCH) * HH + h) * DD;
    #pragma unroll
    for (int i = 0; i < 8; ++i) {
        int idx = tid + 256 * i;
        int t = idx >> 5, mq = idx & 31;
        float4 a = *(float4*)(yt + t * 132 + mq * 4);
        float4 uv = *(const float4*)(usrc + (size_t)t * DD + mq * 4);
        float4 dv = *(const float4*)(Dh + mq * 4);
        float4 r;
        r.x = fmaf(dv.x, uv.x, a.x);
        r.y = fmaf(dv.y, uv.y, a.y);
        r.z = fmaf(dv.z, uv.z, a.z);
        r.w = fmaf(dv.w, uv.w, a.w);
        *(float4*)(yout + (size_t)t * HH * DD + mq * 4) = r;
    }
}

extern "C" void kernel_launch(void* const* d_in, const int* in_sizes, int n_in,
                              void* d_out, int out_size, void* d_ws, size_t ws_size,
                              hipStream_t stream)
{
    const float* u   = (const float*)d_in[0];
    const float* Lre = (const float*)d_in[1];
    const float* Lim = (const float*)d_in[2];
    const float* Bre = (const float*)d_in[3];
    const float* Bim = (const float*)d_in[4];
    const float* Cre = (const float*)d_in[5];
    const float* Cim = (const float*)d_in[6];
    const float* ldt = (const float*)d_in[7];
    const float* Dp  = (const float*)d_in[8];
    float* W = (float*)d_ws;
    unsigned short* SR = (unsigned short*)((char*)d_ws + SB_RE_BYTE);
    unsigned short* SI = (unsigned short*)((char*)d_ws + SB_IM_BYTE);
    short* packB = (short*)((char*)d_ws + PACKB_BYTE);
    short* packC = (short*)((char*)d_ws + PACKC_BYTE);
    float* y = (float*)d_out;

    hipLaunchKernelGGL(k0_precompute, dim3(2), dim3(256), 0, stream,
                       Lre, Lim, Bre, Bim, ldt, W, packB);
    hipLaunchKernelGGL(k0c_packC, dim3(64), dim3(256), 0, stream, Cre, Cim, packC);
    hipLaunchKernelGGL(k1_chunk_state, dim3(BB * HH * NCH), dim3(256), 0, stream,
                       u, W, packB, SR, SI);
    hipLaunchKernelGGL(k2_chunk_scan, dim3(32), dim3(256), 0, stream, W, SR, SI);
    hipLaunchKernelGGL(k3_output, dim3(BB * HH * NCH), dim3(256), 0, stream,
                       u, Dp, W, packB, packC, SR, SI, y);
}